// Round 9
// baseline (412.047 us; speedup 1.0000x reference)
//
#include <hip/hip_runtime.h>
#include <hip/hip_bf16.h>
#include <cfloat>

// Problem constants (fixed by the reference file)
#define NN 4096
#define DD 256
#define MM 5
#define K_TOT 30        // 20 intra + 10 inter
#define CAP 256         // per-mask per-row candidate cap
// Fixed value-space thresholds (sims ~ N(0, sigma), sigma = ||e_i|| in [14,18]):
// capture P(miss) and overflow P(cnt>CAP) both < ~1e-7 across all rows; any
// violation is DETECTED (cnt outside [need,CAP]) and takes the exact fallback.
#define THR_INTRA 20.0f
#define THR_INTER 29.0f

typedef __attribute__((ext_vector_type(8))) short bf16x8;
typedef __attribute__((ext_vector_type(4))) float f32x4;

// async global->LDS, 16 B per lane; LDS dest = wave-uniform base + lane*16
__device__ __forceinline__ void async16(const void* g, void* l) {
    __builtin_amdgcn_global_load_lds((__attribute__((address_space(1))) void*)g,
                                     (__attribute__((address_space(3))) void*)l,
                                     16, 0, 0);
}

// fp64 dot of two fp32 rows — EXACT summation structure shared by normal and
// fallback paths (and identical to the rounds-4..8 validated rescore).
__device__ __forceinline__ double dot_f64(const float* __restrict__ ei,
                                          const float* __restrict__ ej) {
    double a0 = 0, a1 = 0, a2 = 0, a3 = 0;
#pragma unroll 8
    for (int k = 0; k < DD; k += 4) {
        const float4 e4 = *(const float4*)(ej + k);
        a0 = fma((double)ei[k + 0], (double)e4.x, a0);
        a1 = fma((double)ei[k + 1], (double)e4.y, a1);
        a2 = fma((double)ei[k + 2], (double)e4.z, a2);
        a3 = fma((double)ei[k + 3], (double)e4.w, a3);
    }
    return (a0 + a1) + (a2 + a3);
}

// ---------------------------------------------------------------------------
// Kernel 0: E fp32 -> bf16 (RNE) + zero the per-row candidate counters.
// ---------------------------------------------------------------------------
__global__ __launch_bounds__(256) void convert_bf16(const float* __restrict__ E,
                                                    ushort* __restrict__ Eb,
                                                    int* __restrict__ cntG) {
    const int idx = blockIdx.x * 256 + threadIdx.x;
    if (idx < 2 * NN) cntG[idx] = 0;
    const float4 f = ((const float4*)E)[idx];
    ushort4 h;
    {
        __hip_bfloat16 a = __float2bfloat16(f.x); h.x = *(ushort*)&a;
        __hip_bfloat16 b = __float2bfloat16(f.y); h.y = *(ushort*)&b;
        __hip_bfloat16 c = __float2bfloat16(f.z); h.z = *(ushort*)&c;
        __hip_bfloat16 d = __float2bfloat16(f.w); h.w = *(ushort*)&d;
    }
    ((ushort4*)Eb)[idx] = h;
}

// ---------------------------------------------------------------------------
// Kernel 1: FUSED sim-GEMM + candidate selection. The sim matrix is NEVER
// materialized: each 128x128 MFMA tile is compared in-register against the
// fixed thresholds and above-threshold (row, col) pairs are appended to
// per-row global candidate lists. 4 waves (2x2 of 64x64), 16x16x32 MFMA,
// BK=32, global_load_lds width=16 staging with XOR chunk swizzle.
// ---------------------------------------------------------------------------
__global__ __launch_bounds__(256) void gemm_select(const ushort* __restrict__ Eb,
                                                   const int* __restrict__ batch,
                                                   int* __restrict__ cntG,
                                                   int* __restrict__ candG) {
    __shared__ ushort A[128 * 32];   // 8 KB
    __shared__ ushort B[128 * 32];   // 8 KB
    __shared__ int batR[128], batC[128];

    const int t = threadIdx.x;
    const int w = t >> 6, lane = t & 63;
    const int quad = lane >> 4, mr = lane & 15;
    const int rowBase = blockIdx.y * 128, colBase = blockIdx.x * 128;
    const int waveRow = (w & 1) * 64, waveCol = (w >> 1) * 64;

    if (t < 128) batR[t] = batch[rowBase + t];
    else batC[t - 128] = batch[colBase + t - 128];

    const int lrow = lane >> 2;                    // 0..15 row within slab
    const int lslot = lane & 3;                    // LDS chunk slot
    const int gchunk = lslot ^ ((lrow >> 1) & 3);  // swizzled global chunk

    f32x4 acc[4][4];
#pragma unroll
    for (int a = 0; a < 4; ++a)
#pragma unroll
        for (int b = 0; b < 4; ++b) acc[a][b] = (f32x4)(0.0f);

    for (int kc = 0; kc < DD; kc += 32) {
#pragma unroll
        for (int n = 0; n < 2; ++n) {
            const int r = w * 32 + n * 16 + lrow;  // (r>>1)&3 == (lrow>>1)&3
            const ushort* ga = Eb + (size_t)(rowBase + r) * DD + kc + gchunk * 8;
            const ushort* gb = Eb + (size_t)(colBase + r) * DD + kc + gchunk * 8;
            async16(ga, &A[(w * 32 + n * 16) * 32]);
            async16(gb, &B[(w * 32 + n * 16) * 32]);
        }
        __syncthreads();

        const int swzF = (mr >> 1) & 3;
        bf16x8 af[4], bfr[4];
#pragma unroll
        for (int rt = 0; rt < 4; ++rt)
            af[rt] = *(const bf16x8*)&A[(waveRow + rt * 16 + mr) * 32 +
                                        ((quad ^ swzF) * 8)];
#pragma unroll
        for (int ct = 0; ct < 4; ++ct)
            bfr[ct] = *(const bf16x8*)&B[(waveCol + ct * 16 + mr) * 32 +
                                         ((quad ^ swzF) * 8)];
#pragma unroll
        for (int rt = 0; rt < 4; ++rt)
#pragma unroll
            for (int ct = 0; ct < 4; ++ct)
                acc[rt][ct] = __builtin_amdgcn_mfma_f32_16x16x32_bf16(
                    af[rt], bfr[ct], acc[rt][ct], 0, 0, 0);
        __syncthreads();
    }

    // selection epilogue: C/D layout row = quad*4+reg, col = mr (validated)
#pragma unroll
    for (int rt = 0; rt < 4; ++rt)
#pragma unroll
        for (int ct = 0; ct < 4; ++ct)
#pragma unroll
            for (int reg = 0; reg < 4; ++reg) {
                const int row = waveRow + rt * 16 + quad * 4 + reg;
                const int col = waveCol + ct * 16 + mr;
                const float v = acc[rt][ct][reg];
                const int m = (batR[row] == batC[col]) ? 0 : 1;
                if (v >= (m ? THR_INTER : THR_INTRA)) {
                    const int gr = rowBase + row;
                    const int pos = atomicAdd(&cntG[gr * 2 + m], 1);
                    if (pos < CAP) candG[(gr * 2 + m) * CAP + pos] = colBase + col;
                }
            }
}

// ---------------------------------------------------------------------------
// Kernel 2: one block per row. Zeroes this row of the locality output
// (replaces the 67 MB memset), fp64-rescores the captured candidates from
// fp32 E, rank-orders (val desc, idx asc == lax.top_k) and writes knn.
// If capture was out of bounds (detected via cnt), takes an exact full-row
// fp64 fallback (iterative argmax) — correct for ANY input.
// ---------------------------------------------------------------------------
__global__ __launch_bounds__(256) void rescore_rank(const float* __restrict__ E,
                                                    const int* __restrict__ batch,
                                                    const int* __restrict__ cntG,
                                                    const int* __restrict__ candG,
                                                    int* __restrict__ knn,
                                                    float* __restrict__ loc) {
    __shared__ union {
        struct { double vals[2 * CAP]; int idxs[2 * CAP]; } n;   // 6 KB
        struct { double work[NN]; unsigned dead[NN / 32]; } f;   // 32.5 KB
    } u;
    __shared__ float eiL[DD];
    __shared__ double wv[4];
    __shared__ int wi[4];

    const int i = blockIdx.x;
    const int t = threadIdx.x;

    // zero locality row i (16 KB, coalesced)
    {
        const float4 z = make_float4(0.f, 0.f, 0.f, 0.f);
        float4* p = (float4*)(loc + (size_t)i * NN);
#pragma unroll
        for (int k = 0; k < 4; ++k) p[t + k * 256] = z;
    }
    if (t < DD / 4) ((float4*)eiL)[t] = ((const float4*)(E + (size_t)i * DD))[t];
    const int c0 = cntG[i * 2], c1 = cntG[i * 2 + 1];
    __syncthreads();

    const bool ok = (c0 >= 21 && c0 <= CAP && c1 >= 10 && c1 <= CAP);
    if (ok) {
        const int tot = c0 + c1;  // <= 512
        for (int slot = t; slot < tot; slot += 256) {
            const int m = (slot < c0) ? 0 : 1;
            const int s = m ? (slot - c0) : slot;
            const int j = candG[(i * 2 + m) * CAP + s];
            u.n.vals[slot] = dot_f64(eiL, E + (size_t)j * DD);
            u.n.idxs[slot] = j;
        }
        __syncthreads();
        for (int slot = t; slot < tot; slot += 256) {
            const int m = (slot < c0) ? 0 : 1;
            const int lo = m ? c0 : 0, hi = m ? tot : c0;
            const double v = u.n.vals[slot];
            const int idx = u.n.idxs[slot];
            int r = 0;
            for (int s = lo; s < hi; ++s) {
                const double o = u.n.vals[s];
                const int oi = u.n.idxs[s];
                r += (o > v) || (o == v && oi < idx);
            }
            if (m == 0) { if (r >= 1 && r <= 20) knn[i * K_TOT + r - 1] = idx; }
            else        { if (r < 10) knn[i * K_TOT + 20 + r] = idx; }
        }
        return;  // uniform branch
    }

    // ---- exact fallback (detected capture failure; never expected) ----
    const int bi = batch[i];
    for (int e = 0; e < 16; ++e) {
        const int j = t + e * 256;
        u.f.work[j] = dot_f64(eiL, E + (size_t)j * DD);
    }
    if (t < NN / 32) u.f.dead[t] = 0u;
    __syncthreads();

    for (int phase = 0; phase < 2; ++phase) {
        const int rounds = phase ? 10 : 21;
        for (int q = 0; q < rounds; ++q) {
            double bv = -DBL_MAX;
            int bj = 1 << 30;
            for (int e = 0; e < 16; ++e) {
                const int j = t + e * 256;  // ascending j: strict > keeps low idx
                const bool same = (batch[j] == bi);
                const bool want = phase ? !same : same;
                if (want && !((u.f.dead[j >> 5] >> (j & 31)) & 1u)) {
                    const double v = u.f.work[j];
                    if (v > bv) { bv = v; bj = j; }
                }
            }
            for (int off = 32; off; off >>= 1) {
                const double ov = __shfl_down(bv, off);
                const int oj = __shfl_down(bj, off);
                if (ov > bv || (ov == bv && oj < bj)) { bv = ov; bj = oj; }
            }
            if ((t & 63) == 0) { wv[t >> 6] = bv; wi[t >> 6] = bj; }
            __syncthreads();
            if (t == 0) {
                double fv = wv[0];
                int fj = wi[0];
#pragma unroll
                for (int ww = 1; ww < 4; ++ww)
                    if (wv[ww] > fv || (wv[ww] == fv && wi[ww] < fj)) {
                        fv = wv[ww]; fj = wi[ww];
                    }
                if (phase == 0) { if (q > 0) knn[i * K_TOT + q - 1] = fj; }
                else            { knn[i * K_TOT + 20 + q] = fj; }
                u.f.dead[fj >> 5] |= 1u << (fj & 31);
            }
            __syncthreads();
        }
    }
}

// ---------------------------------------------------------------------------
// Kernel 3: mutuality + sparse locality scatter + all_close.
// ---------------------------------------------------------------------------
__global__ __launch_bounds__(256) void finalize_k(const int* __restrict__ knn,
                                                  const float* __restrict__ adj,
                                                  const int* __restrict__ cl,
                                                  float* __restrict__ out) {
    const int gid = blockIdx.x * 256 + threadIdx.x;
    if (gid >= NN * K_TOT) return;
    const int i = gid / K_TOT;
    const int j = knn[gid];

    bool mutual = false;
#pragma unroll
    for (int s = 0; s < K_TOT; ++s) mutual |= (knn[j * K_TOT + s] == i);

    if (mutual) out[(size_t)i * NN + j] = adj[(size_t)i * NN + j];

    bool ac = mutual;
    if (!ac) {
        bool alleq = true;
#pragma unroll
        for (int m = 0; m < MM; ++m) alleq &= (cl[m * NN + i] == cl[m * NN + j]);
        ac = alleq;
    }
    out[(size_t)NN * NN + gid] = ac ? 1.0f : 0.0f;
}

// ---------------------------------------------------------------------------
extern "C" void kernel_launch(void* const* d_in, const int* in_sizes, int n_in,
                              void* d_out, int out_size, void* d_ws, size_t ws_size,
                              hipStream_t stream) {
    const float* adj = (const float*)d_in[0];
    const float* enc = (const float*)d_in[1];
    const int* batch = (const int*)d_in[2];
    const int* cl = (const int*)d_in[3];
    float* out = (float*)d_out;

    // ws layout (~11 MB; prior rounds prove ws >= 36 MB):
    const size_t ebB = (size_t)NN * DD * sizeof(ushort);      // 2.10 MB
    const size_t cntB = (size_t)2 * NN * sizeof(int);         // 32 KB
    const size_t candB = (size_t)NN * 2 * CAP * sizeof(int);  // 8.39 MB
    ushort* Eb = (ushort*)d_ws;
    int* cntG = (int*)((char*)d_ws + ebB);
    int* candG = (int*)((char*)d_ws + ebB + cntB);
    int* knn = (int*)((char*)d_ws + ebB + cntB + candB);

    convert_bf16<<<NN * DD / 4 / 256, 256, 0, stream>>>(enc, Eb, cntG);
    gemm_select<<<dim3(NN / 128, NN / 128), 256, 0, stream>>>(Eb, batch, cntG, candG);
    rescore_rank<<<NN, 256, 0, stream>>>(enc, batch, cntG, candG, knn, out);
    finalize_k<<<NN * K_TOT / 256, 256, 0, stream>>>(knn, adj, cl, out);
}

// Round 10
// 247.647 us; speedup vs baseline: 1.6638x; 1.6638x over previous
//
#include <hip/hip_runtime.h>
#include <hip/hip_bf16.h>
#include <cfloat>

// Problem constants (fixed by the reference file)
#define NN 4096
#define DD 256
#define MM 5
#define K_TOT 30        // 20 intra + 10 inter
#define CAP 128         // per-mask per-row candidate cap (global)
#define MAXB 16         // per-mask per-row per-TILE cap (LDS); overflow -> poison
// Per-row value thresholds: sim_i,j ~ N(0, ||e_i||). z=1.55 intra -> E[cnt]=62+-8
// (need >=21); z=2.10 inter -> E[cnt]=55+-7 (need >=10). Any violation is
// DETECTED via cnt and handled by the exact fallback kernel.
#define Z_INTRA 1.55f
#define Z_INTER 2.10f

typedef __attribute__((ext_vector_type(8))) short bf16x8;
typedef __attribute__((ext_vector_type(4))) float f32x4;

// async global->LDS, 16 B per lane; LDS dest = wave-uniform base + lane*16
__device__ __forceinline__ void async16(const void* g, void* l) {
    __builtin_amdgcn_global_load_lds((__attribute__((address_space(1))) void*)g,
                                     (__attribute__((address_space(3))) void*)l,
                                     16, 0, 0);
}

// fp64 dot of two fp32 rows (sequential form — used by the fallback only)
__device__ __forceinline__ double dot_f64(const float* __restrict__ ei,
                                          const float* __restrict__ ej) {
    double a0 = 0, a1 = 0, a2 = 0, a3 = 0;
#pragma unroll 8
    for (int k = 0; k < DD; k += 4) {
        const float4 e4 = *(const float4*)(ej + k);
        a0 = fma((double)ei[k + 0], (double)e4.x, a0);
        a1 = fma((double)ei[k + 1], (double)e4.y, a1);
        a2 = fma((double)ei[k + 2], (double)e4.z, a2);
        a3 = fma((double)ei[k + 3], (double)e4.w, a3);
    }
    return (a0 + a1) + (a2 + a3);
}

// ---------------------------------------------------------------------------
// Kernel 0: E fp32 -> bf16 (RNE) + per-row norms + zero candidate counters.
// Block = 256 threads = 4 rows; wave w owns row 4*blk+w (64 lanes x float4).
// ---------------------------------------------------------------------------
__global__ __launch_bounds__(256) void convert_bf16(const float* __restrict__ E,
                                                    ushort* __restrict__ Eb,
                                                    float* __restrict__ nrm,
                                                    int* __restrict__ cntG) {
    const int t = threadIdx.x;
    const int idx = blockIdx.x * 256 + t;
    if (idx < 2 * NN) cntG[idx] = 0;
    const float4 f = ((const float4*)E)[idx];
    ushort4 h;
    {
        __hip_bfloat16 a = __float2bfloat16(f.x); h.x = *(ushort*)&a;
        __hip_bfloat16 b = __float2bfloat16(f.y); h.y = *(ushort*)&b;
        __hip_bfloat16 c = __float2bfloat16(f.z); h.z = *(ushort*)&c;
        __hip_bfloat16 d = __float2bfloat16(f.w); h.w = *(ushort*)&d;
    }
    ((ushort4*)Eb)[idx] = h;
    // row norm: butterfly over the wave
    float s = f.x * f.x + f.y * f.y + f.z * f.z + f.w * f.w;
#pragma unroll
    for (int off = 1; off < 64; off <<= 1) s += __shfl_xor(s, off);
    if ((t & 63) == 0) nrm[blockIdx.x * 4 + (t >> 6)] = sqrtf(s);
}

// ---------------------------------------------------------------------------
// Kernel 1: FUSED sim-GEMM + candidate selection; sim never materialized.
// K-loop identical to the R7-validated gemm (global_load_lds width=16, XOR
// chunk swizzle, 16x16x32 MFMA, 4 waves of 64x64). Selection epilogue is
// two-level: LDS per-(row,mask) lists (cheap LDS atomics), then ONE global
// atomicAdd per (row,mask) + bulk copy — no per-element global atomic chains.
// Local overflow (>MAXB) poisons the global count -> detected -> fallback.
// ---------------------------------------------------------------------------
__global__ __launch_bounds__(256) void gemm_select(const ushort* __restrict__ Eb,
                                                   const int* __restrict__ batch,
                                                   const float* __restrict__ nrm,
                                                   int* __restrict__ cntG,
                                                   int* __restrict__ candG) {
    __shared__ union {
        struct { ushort A[128 * 32]; ushort B[128 * 32]; } s;          // 16 KB
        struct { int cnt[128][2]; ushort cand[128][2][MAXB]; } e;      // 9 KB
    } lds;
    __shared__ int batR[128], batC[128];
    __shared__ float thrR[128][2];

    const int t = threadIdx.x;
    const int w = t >> 6, lane = t & 63;
    const int quad = lane >> 4, mr = lane & 15;
    const int rowBase = blockIdx.y * 128, colBase = blockIdx.x * 128;
    const int waveRow = (w & 1) * 64, waveCol = (w >> 1) * 64;

    if (t < 128) {
        batR[t] = batch[rowBase + t];
        const float n = nrm[rowBase + t];
        thrR[t][0] = Z_INTRA * n;
        thrR[t][1] = Z_INTER * n;
    } else {
        batC[t - 128] = batch[colBase + t - 128];
    }

    const int lrow = lane >> 2;                    // 0..15 row within slab
    const int lslot = lane & 3;                    // LDS chunk slot
    const int gchunk = lslot ^ ((lrow >> 1) & 3);  // swizzled global chunk

    f32x4 acc[4][4];
#pragma unroll
    for (int a = 0; a < 4; ++a)
#pragma unroll
        for (int b = 0; b < 4; ++b) acc[a][b] = (f32x4)(0.0f);

    for (int kc = 0; kc < DD; kc += 32) {
#pragma unroll
        for (int n = 0; n < 2; ++n) {
            const int r = w * 32 + n * 16 + lrow;  // (r>>1)&3 == (lrow>>1)&3
            const ushort* ga = Eb + (size_t)(rowBase + r) * DD + kc + gchunk * 8;
            const ushort* gb = Eb + (size_t)(colBase + r) * DD + kc + gchunk * 8;
            async16(ga, &lds.s.A[(w * 32 + n * 16) * 32]);
            async16(gb, &lds.s.B[(w * 32 + n * 16) * 32]);
        }
        __syncthreads();

        const int swzF = (mr >> 1) & 3;
        bf16x8 af[4], bfr[4];
#pragma unroll
        for (int rt = 0; rt < 4; ++rt)
            af[rt] = *(const bf16x8*)&lds.s.A[(waveRow + rt * 16 + mr) * 32 +
                                              ((quad ^ swzF) * 8)];
#pragma unroll
        for (int ct = 0; ct < 4; ++ct)
            bfr[ct] = *(const bf16x8*)&lds.s.B[(waveCol + ct * 16 + mr) * 32 +
                                               ((quad ^ swzF) * 8)];
#pragma unroll
        for (int rt = 0; rt < 4; ++rt)
#pragma unroll
            for (int ct = 0; ct < 4; ++ct)
                acc[rt][ct] = __builtin_amdgcn_mfma_f32_16x16x32_bf16(
                    af[rt], bfr[ct], acc[rt][ct], 0, 0, 0);
        __syncthreads();
    }

    // ---- epilogue level 1: LDS aggregation ----
    ((int*)lds.e.cnt)[t] = 0;   // 128x2 = 256 counters, one per thread
    __syncthreads();
#pragma unroll
    for (int rt = 0; rt < 4; ++rt)
#pragma unroll
        for (int ct = 0; ct < 4; ++ct)
#pragma unroll
            for (int reg = 0; reg < 4; ++reg) {
                const int row = waveRow + rt * 16 + quad * 4 + reg;
                const int col = waveCol + ct * 16 + mr;
                const float v = acc[rt][ct][reg];
                const int m = (batR[row] == batC[col]) ? 0 : 1;
                if (v >= thrR[row][m]) {
                    const int pos = atomicAdd(&lds.e.cnt[row][m], 1);
                    if (pos < MAXB) lds.e.cand[row][m][pos] = (ushort)col;
                }
            }
    __syncthreads();

    // ---- epilogue level 2: one global atomic per (row,mask) + bulk copy ----
    {
        const int row = t >> 1, m = t & 1;
        const int n = lds.e.cnt[row][m];
        if (n > 0) {
            const int gr = rowBase + row;
            const int add = (n > MAXB) ? 100000 : n;  // poison on local overflow
            const int base = atomicAdd(&cntG[gr * 2 + m], add);
            const int ns = min(n, MAXB);
            for (int k = 0; k < ns; ++k)
                if (base + k < CAP)
                    candG[(gr * 2 + m) * CAP + base + k] =
                        colBase + (int)lds.e.cand[row][m][k];
        }
    }
}

// ---------------------------------------------------------------------------
// Kernel 2: one block per row (normal path only). Zeroes the locality row,
// fp64-rescores candidates with ONE WAVE PER CANDIDATE (coalesced 1 KB row
// load: 64 lanes x float4; 4 fp64 FMA/lane; butterfly reduce), rank-orders
// (val desc, idx asc == lax.top_k) and writes knn. Rows with out-of-bounds
// capture are skipped here and handled by fallback_exact.
// ---------------------------------------------------------------------------
__global__ __launch_bounds__(256) void rescore_rank(const float* __restrict__ E,
                                                    const int* __restrict__ cntG,
                                                    const int* __restrict__ candG,
                                                    int* __restrict__ knn,
                                                    float* __restrict__ loc) {
    __shared__ double vals[2 * CAP];
    __shared__ int idxs[2 * CAP];

    const int i = blockIdx.x;
    const int t = threadIdx.x;
    const int w = t >> 6, lane = t & 63;

    // zero locality row i (16 KB, coalesced)
    {
        const float4 z = make_float4(0.f, 0.f, 0.f, 0.f);
        float4* p = (float4*)(loc + (size_t)i * NN);
#pragma unroll
        for (int k = 0; k < 4; ++k) p[t + k * 256] = z;
    }

    const int c0r = cntG[i * 2], c1r = cntG[i * 2 + 1];
    const bool ok = (c0r >= 21 && c0r <= CAP && c1r >= 10 && c1r <= CAP);
    if (!ok) return;  // fallback_exact owns this row
    const int c0 = c0r, c1 = c1r, tot = c0 + c1;  // tot <= 256

    // load candidate indices into LDS (coalesced)
    if (t < tot) {
        const int m = (t < c0) ? 0 : 1;
        const int s = m ? (t - c0) : t;
        idxs[t] = candG[(i * 2 + m) * CAP + s];
    }
    __syncthreads();

    // this wave's slice of e_i (float4 per lane), reused across candidates
    const float4 eif = ((const float4*)(E + (size_t)i * DD))[lane];

    for (int slot = w; slot < tot; slot += 4) {
        const int j = idxs[slot];
        const float4 ejf = ((const float4*)(E + (size_t)j * DD))[lane];
        double d = fma((double)eif.x, (double)ejf.x,
                   fma((double)eif.y, (double)ejf.y,
                   fma((double)eif.z, (double)ejf.z,
                       (double)eif.w * (double)ejf.w)));
#pragma unroll
        for (int off = 1; off < 64; off <<= 1) d += __shfl_xor(d, off);
        if (lane == 0) vals[slot] = d;
    }
    __syncthreads();

    // rank-based ordered output (ties: lower index first)
    if (t < tot) {
        const int m = (t < c0) ? 0 : 1;
        const int lo = m ? c0 : 0, hi = m ? tot : c0;
        const double v = vals[t];
        const int idx = idxs[t];
        int r = 0;
        for (int s = lo; s < hi; ++s) {
            const double o = vals[s];
            const int oi = idxs[s];
            r += (o > v) || (o == v && oi < idx);
        }
        if (m == 0) { if (r >= 1 && r <= 20) knn[i * K_TOT + r - 1] = idx; }
        else        { if (r < 10) knn[i * K_TOT + 20 + r] = idx; }
    }
}

// ---------------------------------------------------------------------------
// Kernel 2b: exact fallback for rows whose capture was out of bounds
// (detected via cntG). Early-exits for ok rows (~all). Full fp64 row +
// iterative argmax, exact lax.top_k semantics — correct for ANY input.
// ---------------------------------------------------------------------------
__global__ __launch_bounds__(256) void fallback_exact(const float* __restrict__ E,
                                                      const int* __restrict__ batch,
                                                      const int* __restrict__ cntG,
                                                      int* __restrict__ knn) {
    const int i = blockIdx.x;
    const int c0 = cntG[i * 2], c1 = cntG[i * 2 + 1];
    if (c0 >= 21 && c0 <= CAP && c1 >= 10 && c1 <= CAP) return;

    __shared__ double work[NN];
    __shared__ unsigned dead[NN / 32];
    __shared__ float eiL[DD];
    __shared__ double wv[4];
    __shared__ int wi[4];

    const int t = threadIdx.x;
    const int bi = batch[i];
    if (t < DD / 4) ((float4*)eiL)[t] = ((const float4*)(E + (size_t)i * DD))[t];
    if (t < NN / 32) dead[t] = 0u;
    __syncthreads();
    for (int e = 0; e < 16; ++e) {
        const int j = t + e * 256;
        work[j] = dot_f64(eiL, E + (size_t)j * DD);
    }
    __syncthreads();

    for (int phase = 0; phase < 2; ++phase) {
        const int rounds = phase ? 10 : 21;
        for (int q = 0; q < rounds; ++q) {
            double bv = -DBL_MAX;
            int bj = 1 << 30;
            for (int e = 0; e < 16; ++e) {
                const int j = t + e * 256;  // ascending j: strict > keeps low idx
                const bool same = (batch[j] == bi);
                const bool want = phase ? !same : same;
                if (want && !((dead[j >> 5] >> (j & 31)) & 1u)) {
                    const double v = work[j];
                    if (v > bv) { bv = v; bj = j; }
                }
            }
            for (int off = 32; off; off >>= 1) {
                const double ov = __shfl_down(bv, off);
                const int oj = __shfl_down(bj, off);
                if (ov > bv || (ov == bv && oj < bj)) { bv = ov; bj = oj; }
            }
            if ((t & 63) == 0) { wv[t >> 6] = bv; wi[t >> 6] = bj; }
            __syncthreads();
            if (t == 0) {
                double fv = wv[0];
                int fj = wi[0];
#pragma unroll
                for (int ww = 1; ww < 4; ++ww)
                    if (wv[ww] > fv || (wv[ww] == fv && wi[ww] < fj)) {
                        fv = wv[ww]; fj = wi[ww];
                    }
                if (phase == 0) { if (q > 0) knn[i * K_TOT + q - 1] = fj; }
                else            { knn[i * K_TOT + 20 + q] = fj; }
                dead[fj >> 5] |= 1u << (fj & 31);
            }
            __syncthreads();
        }
    }
}

// ---------------------------------------------------------------------------
// Kernel 3: mutuality + sparse locality scatter + all_close.
// ---------------------------------------------------------------------------
__global__ __launch_bounds__(256) void finalize_k(const int* __restrict__ knn,
                                                  const float* __restrict__ adj,
                                                  const int* __restrict__ cl,
                                                  float* __restrict__ out) {
    const int gid = blockIdx.x * 256 + threadIdx.x;
    if (gid >= NN * K_TOT) return;
    const int i = gid / K_TOT;
    const int j = knn[gid];

    bool mutual = false;
#pragma unroll
    for (int s = 0; s < K_TOT; ++s) mutual |= (knn[j * K_TOT + s] == i);

    if (mutual) out[(size_t)i * NN + j] = adj[(size_t)i * NN + j];

    bool ac = mutual;
    if (!ac) {
        bool alleq = true;
#pragma unroll
        for (int m = 0; m < MM; ++m) alleq &= (cl[m * NN + i] == cl[m * NN + j]);
        ac = alleq;
    }
    out[(size_t)NN * NN + gid] = ac ? 1.0f : 0.0f;
}

// ---------------------------------------------------------------------------
extern "C" void kernel_launch(void* const* d_in, const int* in_sizes, int n_in,
                              void* d_out, int out_size, void* d_ws, size_t ws_size,
                              hipStream_t stream) {
    const float* adj = (const float*)d_in[0];
    const float* enc = (const float*)d_in[1];
    const int* batch = (const int*)d_in[2];
    const int* cl = (const int*)d_in[3];
    float* out = (float*)d_out;

    // ws layout (~7 MB)
    const size_t ebB = (size_t)NN * DD * sizeof(ushort);      // 2.10 MB
    const size_t nrmB = (size_t)NN * sizeof(float);           // 16 KB
    const size_t cntB = (size_t)2 * NN * sizeof(int);         // 32 KB
    const size_t candB = (size_t)NN * 2 * CAP * sizeof(int);  // 4.19 MB
    ushort* Eb = (ushort*)d_ws;
    float* nrm = (float*)((char*)d_ws + ebB);
    int* cntG = (int*)((char*)d_ws + ebB + nrmB);
    int* candG = (int*)((char*)d_ws + ebB + nrmB + cntB);
    int* knn = (int*)((char*)d_ws + ebB + nrmB + cntB + candB);

    convert_bf16<<<NN * DD / 4 / 256, 256, 0, stream>>>(enc, Eb, nrm, cntG);
    gemm_select<<<dim3(NN / 128, NN / 128), 256, 0, stream>>>(Eb, batch, nrm, cntG, candG);
    rescore_rank<<<NN, 256, 0, stream>>>(enc, cntG, candG, knn, out);
    fallback_exact<<<NN, 256, 0, stream>>>(enc, batch, cntG, knn);
    finalize_k<<<NN * K_TOT / 256, 256, 0, stream>>>(knn, adj, cl, out);
}